// Round 11
// baseline (288.996 us; speedup 1.0000x reference)
//
#include <hip/hip_runtime.h>

#define NN 100000
#define NE 1000000
#define DIM 64
#define ZPITCH 200          // LDS row pitch in ushort for transform tile
#define PAD4(c) (((c) + 3) & ~3)
#define CAP 32              // fixed bucket capacity per (dst,rel) segment
#define SENT (2 * NN * CAP) // sentinel quad index (zero-row gather target)
#define FGRID ((NE / 4 + 255) / 256)      // 977 fill blocks: 4 edges/thread
#define G_INIT 6251         // esrc init: 1,600,001 int4 stores of NN
#define G_ZC 196            // cnt2 zero: 50,000 int4 stores
#define G_CONV 6250         // feature convert: NN*16 float4s exactly

typedef __attribute__((ext_vector_type(4))) float f32x4;
typedef __attribute__((ext_vector_type(8))) _Float16 h8;

union HU4 { uint4 u; h8 h; };

__device__ __forceinline__ ushort f2h(float f) {
    union { _Float16 h; ushort u; } c; c.h = (_Float16)f; return c.u;
}

// ---------------- MEGA front-end (all independent prep work, one launch) ----
//   [0, G_INIT):            esrc = NN everywhere (pads + sentinel pre-written;
//                           replaces the separate pad_fill kernel entirely)
//   [G_INIT, +G_ZC):        cnt2 cursors = 0
//   [.., +G_CONV):          feature convert f32 -> f16
//   next block:             zero row NN of both feature tables
//   [.., +144):             weight prep f16 of [W0;W1;Ws] x 3 layers
__global__ __launch_bounds__(256) void front_end(
    int* __restrict__ esrc, int* __restrict__ cnt2,
    const float* __restrict__ x, ushort* __restrict__ xb, ushort* __restrict__ xb1,
    const float* __restrict__ W0, const float* __restrict__ Ws0,
    const float* __restrict__ W1, const float* __restrict__ Ws1,
    const float* __restrict__ W2, const float* __restrict__ Ws2,
    ushort* __restrict__ wt)
{
    int b = blockIdx.x;
    if (b < G_INIT) {
        int i = b * 256 + threadIdx.x;
        if (i < (2 * NN * CAP + 4) / 4) {        // 1,600,001 int4s exactly
            int4 v = {NN, NN, NN, NN};
            *(int4*)(esrc + (size_t)i * 4) = v;
        }
    } else if (b < G_INIT + G_ZC) {
        int i = (b - G_INIT) * 256 + threadIdx.x;
        if (i < 2 * NN / 4) {
            int4 z = {0, 0, 0, 0};
            *(int4*)(cnt2 + (size_t)i * 4) = z;
        }
    } else if (b < G_INIT + G_ZC + G_CONV) {     // convert: NN*16 float4s
        int i = (b - G_INIT - G_ZC) * 256 + threadIdx.x;
        float4 v = ((const float4*)x)[i];
        union { ushort u[4]; uint2 w; } o;
        o.u[0] = f2h(v.x); o.u[1] = f2h(v.y); o.u[2] = f2h(v.z); o.u[3] = f2h(v.w);
        *(uint2*)(xb + (size_t)i * 4) = o.w;
    } else if (b == G_INIT + G_ZC + G_CONV) {    // zero row NN of both tables
        int t = threadIdx.x;
        if (t < 64) {
            xb[(size_t)NN * DIM + t] = 0;
            xb1[(size_t)NN * DIM + t] = 0;
        }
    } else {                                     // weight prep, 144 blocks
        int idx = (b - G_INIT - G_ZC - G_CONV - 1) * 256 + threadIdx.x;
        int l = idx / 12288, rr = idx % 12288;
        const float* W  = (l == 0) ? W0 : (l == 1) ? W1 : W2;
        const float* Ws = (l == 0) ? Ws0 : (l == 1) ? Ws1 : Ws2;
        int k = rr >> 6, n = rr & 63;
        float v = (k < 128) ? W[k * 64 + n] : Ws[(k - 128) * 64 + n];
        wt[l * 12288 + n * 192 + k] = f2h(v);
    }
}

// ---------------- Bucket CSR fill: ONE atomic pass --------------------------
// The returning atomicAdd IS the segment rank; scatter src straight into the
// (dst,rel) bucket at key*CAP + rank. Poisson(5) over 200K buckets -> max
// count ~18 << CAP=32, no overflow. Slots beyond the count keep their
// pre-initialized NN (zero-row gather target), so no pad pass is needed.
__global__ __launch_bounds__(256) void fill_direct(const int* __restrict__ src,
                                                   const int* __restrict__ dst,
                                                   const int* __restrict__ et,
                                                   int* __restrict__ cur,
                                                   int* __restrict__ esrc) {
    int e = (blockIdx.x * 256 + threadIdx.x) * 4;
    if (e >= NE) return;
    int4 d4 = *(const int4*)(dst + e);
    int4 t4 = *(const int4*)(et + e);
    int4 s4 = *(const int4*)(src + e);
    int k0 = d4.x * 2 + t4.x;
    int k1 = d4.y * 2 + t4.y;
    int k2 = d4.z * 2 + t4.z;
    int k3 = d4.w * 2 + t4.w;
    int r0 = atomicAdd(&cur[k0], 1);
    int r1 = atomicAdd(&cur[k1], 1);
    int r2 = atomicAdd(&cur[k2], 1);
    int r3 = atomicAdd(&cur[k3], 1);
    esrc[k0 * CAP + r0] = s4.x;
    esrc[k1 * CAP + r1] = s4.y;
    esrc[k2 * CAP + r2] = s4.z;
    esrc[k3 * CAP + r3] = s4.w;
}

// ---------------- Aggregation v10b: 8-lane groups, bucket layout ------------
// xb4: (NN+1)-row f16 table viewed as uint4 (8 dims / 16 B, 8/row).
// Each 8-lane group owns ONE node; segments at fixed n*2*CAP / n*2*CAP+CAP.
// Dual-chain (rel0 + rel1 in flight); finished chains redirect to the
// sentinel quad (zero-row gathers).
__global__ __launch_bounds__(256) void rgcn_aggregate_g4(
    const uint4* __restrict__ xb4, const int* __restrict__ cnt2,
    const int* __restrict__ esrc,
    uint4* __restrict__ agg4)      // NN x 16 uint4: [rel0 8 | rel1 8]
{
    int t = threadIdx.x, lane = t & 63, wid = t >> 6;
    int g = lane >> 3, s = lane & 7;
    int n = blockIdx.x * 32 + wid * 8 + g;   // grid 3125 -> exactly NN
    int2 c = *(const int2*)(cnt2 + 2 * n);
    int c0p = PAD4(c.x), c1p = PAD4(c.y);
    int tmax = c0p > c1p ? c0p : c1p;
    int base0 = n * 2 * CAP;
    int base1 = base0 + CAP;

    const uint4* xrow = xb4 + s;
    HU4 z; z.u.x = 0u; z.u.y = 0u; z.u.z = 0u; z.u.w = 0u;
    h8 a0 = z.h, a1 = z.h;

#pragma unroll 2
    for (int j = 0; j < tmax; j += 4) {
        int i0 = (j < c0p) ? base0 + j : SENT;
        int i1 = (j < c1p) ? base1 + j : SENT;
        int4 qa = *(const int4*)(esrc + i0);
        int4 qb = *(const int4*)(esrc + i1);
        HU4 w0, w1, w2, w3, w4, w5, w6, w7;
        w0.u = xrow[(size_t)qa.x * 8];
        w1.u = xrow[(size_t)qa.y * 8];
        w2.u = xrow[(size_t)qa.z * 8];
        w3.u = xrow[(size_t)qa.w * 8];
        w4.u = xrow[(size_t)qb.x * 8];
        w5.u = xrow[(size_t)qb.y * 8];
        w6.u = xrow[(size_t)qb.z * 8];
        w7.u = xrow[(size_t)qb.w * 8];
        a0 += w0.h; a0 += w1.h; a0 += w2.h; a0 += w3.h;
        a1 += w4.h; a1 += w5.h; a1 += w6.h; a1 += w7.h;
    }

    // Row layout (matches transform): 128 f16 = [rel0 dims 0..63 | rel1].
    HU4 o0, o1; o0.h = a0; o1.h = a1;
    agg4[(size_t)n * 16 + s] = o0.u;
    agg4[(size_t)n * 16 + 8 + s] = o1.u;
}

// ---------------- MFMA transform (f16, LDS-staged — proven R7 version) ------
__global__ __launch_bounds__(256) void rgcn_transform_mfma(
    const ushort* __restrict__ agg,   // [NN][128] f16
    const ushort* __restrict__ xb,    // [NN][64]  f16
    const ushort* __restrict__ wt,    // [64][192] f16
    const float* __restrict__ bias,
    float* __restrict__ outf,
    ushort* __restrict__ xbn,
    int mode)
{
    __shared__ ushort sZ[64 * ZPITCH];   // 25.6 KB

    int t = threadIdx.x, lane = t & 63, wid = t >> 6;
    int quad = lane >> 4, l16 = lane & 15;

    h8 bh[6];
    {
        const ushort* wh = wt + (size_t)(wid * 16 + l16) * 192;
#pragma unroll
        for (int kk = 0; kk < 6; ++kk)
            bh[kk] = *(const h8*)(wh + kk * 32 + quad * 8);
    }
    float bv = bias[wid * 16 + l16];

    int n0 = blockIdx.x * 64;
    for (int i = t; i < 1024; i += 256) {           // agg: 64 rows x 16 uint4
        int node = i >> 4, c8 = i & 15;
        int n = n0 + node;
        uint4 v = {0u, 0u, 0u, 0u};
        if (n < NN) v = *(const uint4*)(agg + (size_t)n * 128 + c8 * 8);
        *(uint4*)(sZ + node * ZPITCH + c8 * 8) = v;
    }
    for (int i = t; i < 512; i += 256) {            // xb: 64 rows x 8 uint4
        int node = i >> 3, c8 = i & 7;
        int n = n0 + node;
        uint4 v = {0u, 0u, 0u, 0u};
        if (n < NN) v = *(const uint4*)(xb + (size_t)n * DIM + c8 * 8);
        *(uint4*)(sZ + node * ZPITCH + 128 + c8 * 8) = v;
    }
    __syncthreads();

    f32x4 acc[4];
#pragma unroll
    for (int mt = 0; mt < 4; ++mt) acc[mt] = (f32x4){bv, bv, bv, bv};

#pragma unroll
    for (int kk = 0; kk < 6; ++kk) {
#pragma unroll
        for (int mt = 0; mt < 4; ++mt) {
            h8 a = *(const h8*)(sZ + (mt * 16 + l16) * ZPITCH + kk * 32 + quad * 8);
            acc[mt] = __builtin_amdgcn_mfma_f32_16x16x32_f16(a, bh[kk], acc[mt], 0, 0, 0);
        }
    }

    int col = wid * 16 + l16;
#pragma unroll
    for (int mt = 0; mt < 4; ++mt) {
#pragma unroll
        for (int r = 0; r < 4; ++r) {
            int node = n0 + mt * 16 + quad * 4 + r;
            if (node < NN) {
                float v = acc[mt][r];
                if (mode) outf[(size_t)node * DIM + col] = v;
                else      xbn[(size_t)node * DIM + col] = f2h(fmaxf(v, 0.f));
            }
        }
    }
}

extern "C" void kernel_launch(void* const* d_in, const int* in_sizes, int n_in,
                              void* d_out, int out_size, void* d_ws, size_t ws_size,
                              hipStream_t stream)
{
    const float* feat = (const float*)d_in[0];
    const int*   src  = (const int*)d_in[1];
    const int*   dst  = (const int*)d_in[2];
    const int*   et   = (const int*)d_in[3];
    const float* W[3]  = { (const float*)d_in[4], (const float*)d_in[7], (const float*)d_in[10] };
    const float* Ws[3] = { (const float*)d_in[5], (const float*)d_in[8], (const float*)d_in[11] };
    const float* b[3]  = { (const float*)d_in[6], (const float*)d_in[9], (const float*)d_in[12] };

    // Workspace (~78 MB):
    //   agg   uint[NN*64]             25.6 MB
    //   xbuf0/xbuf1 ushort[(NN+1)*64] 2 x 12.8 MB (row NN = zero row)
    //   wt ushort[3][12288]
    //   esrc int[2*NN*CAP + 4]        25.6 MB fixed buckets + sentinel quad
    //                                 (fully pre-initialized to NN)
    //   cnt2 int[2NN]                 cursors -> per-(dst,rel) counts
    uint*   agg   = (uint*)d_ws;
    ushort* xbuf0 = (ushort*)(agg + (size_t)NN * 64);
    ushort* xbuf1 = xbuf0 + (size_t)(NN + 1) * DIM;
    ushort* wt    = xbuf1 + (size_t)(NN + 1) * DIM;
    int* esrc    = (int*)(wt + 3 * 12288);
    int* cnt2    = esrc + 2 * NN * CAP + 4;
    float* outF  = (float*)d_out;

    const dim3 tb(256);
    const int fgrid = G_INIT + G_ZC + G_CONV + 1 + 144;   // 12842
    const int tgrid = (NN + 63) / 64;         // 1563
    const int agrid = NN / 32;                // 3125

    // 1 launch: all independent prep (esrc init, cursor zero, convert, weights)
    front_end<<<fgrid, tb, 0, stream>>>(esrc, cnt2, feat, xbuf0, xbuf1,
                                        W[0], Ws[0], W[1], Ws[1], W[2], Ws[2], wt);
    // 1 launch: one-pass bucket CSR fill
    fill_direct<<<FGRID, tb, 0, stream>>>(src, dst, et, cnt2, esrc);

    // Layer 0: xbuf0 -> xbuf1 = f16(relu(out0))
    rgcn_aggregate_g4<<<agrid, tb, 0, stream>>>((const uint4*)xbuf0, cnt2, esrc, (uint4*)agg);
    rgcn_transform_mfma<<<tgrid, tb, 0, stream>>>((const ushort*)agg, xbuf0, wt, b[0], nullptr, xbuf1, 0);
    // Layer 1: xbuf1 -> xbuf0
    rgcn_aggregate_g4<<<agrid, tb, 0, stream>>>((const uint4*)xbuf1, cnt2, esrc, (uint4*)agg);
    rgcn_transform_mfma<<<tgrid, tb, 0, stream>>>((const ushort*)agg, xbuf1, wt + 12288, b[1], nullptr, xbuf0, 0);
    // Layer 2: xbuf0 -> d_out (fp32, no activation)
    rgcn_aggregate_g4<<<agrid, tb, 0, stream>>>((const uint4*)xbuf0, cnt2, esrc, (uint4*)agg);
    rgcn_transform_mfma<<<tgrid, tb, 0, stream>>>((const ushort*)agg, xbuf0, wt + 2 * 12288, b[2], outF, nullptr, 1);
}

// Round 12
// 284.050 us; speedup vs baseline: 1.0174x; 1.0174x over previous
//
#include <hip/hip_runtime.h>

#define NN 100000
#define NE 1000000
#define DIM 64
#define ZPITCH 200          // LDS row pitch in ushort for transform tile
#define PAD4(c) (((c) + 3) & ~3)
#define CAP 32              // fixed bucket capacity per (dst,rel) segment
#define SENT (2 * NN * CAP) // sentinel quad index ({NN,NN,NN,NN})
#define FGRID ((NE / 4 + 255) / 256)      // 977 fill blocks: 4 edges/thread
#define G_ZC 196            // cnt2 zero: 50,000 int4 stores
#define G_CONV 6250         // feature convert: NN*16 float4s exactly

typedef __attribute__((ext_vector_type(4))) float f32x4;
typedef __attribute__((ext_vector_type(8))) _Float16 h8;

union HU4 { uint4 u; h8 h; };

__device__ __forceinline__ ushort f2h(float f) {
    union { _Float16 h; ushort u; } c; c.h = (_Float16)f; return c.u;
}

// ---------------- Front-end (independent prep, one launch; NO esrc init) ----
//   [0, G_ZC):       cnt2 cursors = 0
//   [G_ZC, +G_CONV): feature convert f32 -> f16
//   next block:      zero row NN of both feature tables + sentinel quad
//   [.., +144):      weight prep f16 of [W0;W1;Ws] x 3 layers
// esrc stays UNINITIALIZED (fill_direct runs against a clean L2 -- the R11
// pre-init put 25.6 MB of dirty lines in L2 and cost fill +15us); garbage
// slots are masked in-register by the aggregate, never used as addresses.
__global__ __launch_bounds__(256) void front_end(
    int* __restrict__ esrc, int* __restrict__ cnt2,
    const float* __restrict__ x, ushort* __restrict__ xb, ushort* __restrict__ xb1,
    const float* __restrict__ W0, const float* __restrict__ Ws0,
    const float* __restrict__ W1, const float* __restrict__ Ws1,
    const float* __restrict__ W2, const float* __restrict__ Ws2,
    ushort* __restrict__ wt)
{
    int b = blockIdx.x;
    if (b < G_ZC) {
        int i = b * 256 + threadIdx.x;
        if (i < 2 * NN / 4) {
            int4 z = {0, 0, 0, 0};
            *(int4*)(cnt2 + (size_t)i * 4) = z;
        }
    } else if (b < G_ZC + G_CONV) {              // convert: NN*16 float4s
        int i = (b - G_ZC) * 256 + threadIdx.x;
        float4 v = ((const float4*)x)[i];
        union { ushort u[4]; uint2 w; } o;
        o.u[0] = f2h(v.x); o.u[1] = f2h(v.y); o.u[2] = f2h(v.z); o.u[3] = f2h(v.w);
        *(uint2*)(xb + (size_t)i * 4) = o.w;
    } else if (b == G_ZC + G_CONV) {             // zero rows + sentinel quad
        int t = threadIdx.x;
        if (t < 64) {
            xb[(size_t)NN * DIM + t] = 0;
            xb1[(size_t)NN * DIM + t] = 0;
        } else if (t < 68) {
            esrc[SENT + (t - 64)] = NN;
        }
    } else {                                     // weight prep, 144 blocks
        int idx = (b - G_ZC - G_CONV - 1) * 256 + threadIdx.x;
        int l = idx / 12288, rr = idx % 12288;
        const float* W  = (l == 0) ? W0 : (l == 1) ? W1 : W2;
        const float* Ws = (l == 0) ? Ws0 : (l == 1) ? Ws1 : Ws2;
        int k = rr >> 6, n = rr & 63;
        float v = (k < 128) ? W[k * 64 + n] : Ws[(k - 128) * 64 + n];
        wt[l * 12288 + n * 192 + k] = f2h(v);
    }
}

// ---------------- Bucket CSR fill: ONE atomic pass --------------------------
// The returning atomicAdd IS the segment rank; scatter src straight into the
// (dst,rel) bucket at key*CAP + rank. Poisson(5) over 200K buckets -> max
// count ~18 << CAP=32, no overflow. Slots beyond the count remain garbage;
// the aggregate masks them in-register (no pad pass, no esrc init).
__global__ __launch_bounds__(256) void fill_direct(const int* __restrict__ src,
                                                   const int* __restrict__ dst,
                                                   const int* __restrict__ et,
                                                   int* __restrict__ cur,
                                                   int* __restrict__ esrc) {
    int e = (blockIdx.x * 256 + threadIdx.x) * 4;
    if (e >= NE) return;
    int4 d4 = *(const int4*)(dst + e);
    int4 t4 = *(const int4*)(et + e);
    int4 s4 = *(const int4*)(src + e);
    int k0 = d4.x * 2 + t4.x;
    int k1 = d4.y * 2 + t4.y;
    int k2 = d4.z * 2 + t4.z;
    int k3 = d4.w * 2 + t4.w;
    int r0 = atomicAdd(&cur[k0], 1);
    int r1 = atomicAdd(&cur[k1], 1);
    int r2 = atomicAdd(&cur[k2], 1);
    int r3 = atomicAdd(&cur[k3], 1);
    esrc[k0 * CAP + r0] = s4.x;
    esrc[k1 * CAP + r1] = s4.y;
    esrc[k2 * CAP + r2] = s4.z;
    esrc[k3 * CAP + r3] = s4.w;
}

// ---------------- Aggregation v11: 8-lane groups, in-register pad masking ---
// xb4: (NN+1)-row f16 table viewed as uint4 (8 dims / 16 B, 8/row).
// Each 8-lane group owns ONE node; segments at fixed n*2*CAP / n*2*CAP+CAP.
// Dual-chain (rel0 + rel1 in flight). Tail quads contain GARBAGE beyond the
// raw count: each index is selected against the raw count before use as a
// gather address ((j+k < c) ? q[k] : NN) -- 8 uniform-condition cndmasks per
// iteration; all gather addresses provably in [0, NN].
__global__ __launch_bounds__(256) void rgcn_aggregate_g4(
    const uint4* __restrict__ xb4, const int* __restrict__ cnt2,
    const int* __restrict__ esrc,
    uint4* __restrict__ agg4)      // NN x 16 uint4: [rel0 8 | rel1 8]
{
    int t = threadIdx.x, lane = t & 63, wid = t >> 6;
    int g = lane >> 3, s = lane & 7;
    int n = blockIdx.x * 32 + wid * 8 + g;   // grid 3125 -> exactly NN
    int2 c = *(const int2*)(cnt2 + 2 * n);
    int c0 = c.x, c1 = c.y;
    int c0p = PAD4(c0), c1p = PAD4(c1);
    int tmax = c0p > c1p ? c0p : c1p;
    int base0 = n * 2 * CAP;
    int base1 = base0 + CAP;

    const uint4* xrow = xb4 + s;
    HU4 z; z.u.x = 0u; z.u.y = 0u; z.u.z = 0u; z.u.w = 0u;
    h8 a0 = z.h, a1 = z.h;

#pragma unroll 2
    for (int j = 0; j < tmax; j += 4) {
        int i0 = (j < c0p) ? base0 + j : SENT;
        int i1 = (j < c1p) ? base1 + j : SENT;
        int4 qa = *(const int4*)(esrc + i0);
        int4 qb = *(const int4*)(esrc + i1);
        int p0 = (j + 0 < c0) ? qa.x : NN;
        int p1 = (j + 1 < c0) ? qa.y : NN;
        int p2 = (j + 2 < c0) ? qa.z : NN;
        int p3 = (j + 3 < c0) ? qa.w : NN;
        int p4 = (j + 0 < c1) ? qb.x : NN;
        int p5 = (j + 1 < c1) ? qb.y : NN;
        int p6 = (j + 2 < c1) ? qb.z : NN;
        int p7 = (j + 3 < c1) ? qb.w : NN;
        HU4 w0, w1, w2, w3, w4, w5, w6, w7;
        w0.u = xrow[(size_t)p0 * 8];
        w1.u = xrow[(size_t)p1 * 8];
        w2.u = xrow[(size_t)p2 * 8];
        w3.u = xrow[(size_t)p3 * 8];
        w4.u = xrow[(size_t)p4 * 8];
        w5.u = xrow[(size_t)p5 * 8];
        w6.u = xrow[(size_t)p6 * 8];
        w7.u = xrow[(size_t)p7 * 8];
        a0 += w0.h; a0 += w1.h; a0 += w2.h; a0 += w3.h;
        a1 += w4.h; a1 += w5.h; a1 += w6.h; a1 += w7.h;
    }

    // Row layout (matches transform): 128 f16 = [rel0 dims 0..63 | rel1].
    HU4 o0, o1; o0.h = a0; o1.h = a1;
    agg4[(size_t)n * 16 + s] = o0.u;
    agg4[(size_t)n * 16 + 8 + s] = o1.u;
}

// ---------------- MFMA transform (f16, LDS-staged — proven R7 version) ------
__global__ __launch_bounds__(256) void rgcn_transform_mfma(
    const ushort* __restrict__ agg,   // [NN][128] f16
    const ushort* __restrict__ xb,    // [NN][64]  f16
    const ushort* __restrict__ wt,    // [64][192] f16
    const float* __restrict__ bias,
    float* __restrict__ outf,
    ushort* __restrict__ xbn,
    int mode)
{
    __shared__ ushort sZ[64 * ZPITCH];   // 25.6 KB

    int t = threadIdx.x, lane = t & 63, wid = t >> 6;
    int quad = lane >> 4, l16 = lane & 15;

    h8 bh[6];
    {
        const ushort* wh = wt + (size_t)(wid * 16 + l16) * 192;
#pragma unroll
        for (int kk = 0; kk < 6; ++kk)
            bh[kk] = *(const h8*)(wh + kk * 32 + quad * 8);
    }
    float bv = bias[wid * 16 + l16];

    int n0 = blockIdx.x * 64;
    for (int i = t; i < 1024; i += 256) {           // agg: 64 rows x 16 uint4
        int node = i >> 4, c8 = i & 15;
        int n = n0 + node;
        uint4 v = {0u, 0u, 0u, 0u};
        if (n < NN) v = *(const uint4*)(agg + (size_t)n * 128 + c8 * 8);
        *(uint4*)(sZ + node * ZPITCH + c8 * 8) = v;
    }
    for (int i = t; i < 512; i += 256) {            // xb: 64 rows x 8 uint4
        int node = i >> 3, c8 = i & 7;
        int n = n0 + node;
        uint4 v = {0u, 0u, 0u, 0u};
        if (n < NN) v = *(const uint4*)(xb + (size_t)n * DIM + c8 * 8);
        *(uint4*)(sZ + node * ZPITCH + 128 + c8 * 8) = v;
    }
    __syncthreads();

    f32x4 acc[4];
#pragma unroll
    for (int mt = 0; mt < 4; ++mt) acc[mt] = (f32x4){bv, bv, bv, bv};

#pragma unroll
    for (int kk = 0; kk < 6; ++kk) {
#pragma unroll
        for (int mt = 0; mt < 4; ++mt) {
            h8 a = *(const h8*)(sZ + (mt * 16 + l16) * ZPITCH + kk * 32 + quad * 8);
            acc[mt] = __builtin_amdgcn_mfma_f32_16x16x32_f16(a, bh[kk], acc[mt], 0, 0, 0);
        }
    }

    int col = wid * 16 + l16;
#pragma unroll
    for (int mt = 0; mt < 4; ++mt) {
#pragma unroll
        for (int r = 0; r < 4; ++r) {
            int node = n0 + mt * 16 + quad * 4 + r;
            if (node < NN) {
                float v = acc[mt][r];
                if (mode) outf[(size_t)node * DIM + col] = v;
                else      xbn[(size_t)node * DIM + col] = f2h(fmaxf(v, 0.f));
            }
        }
    }
}

extern "C" void kernel_launch(void* const* d_in, const int* in_sizes, int n_in,
                              void* d_out, int out_size, void* d_ws, size_t ws_size,
                              hipStream_t stream)
{
    const float* feat = (const float*)d_in[0];
    const int*   src  = (const int*)d_in[1];
    const int*   dst  = (const int*)d_in[2];
    const int*   et   = (const int*)d_in[3];
    const float* W[3]  = { (const float*)d_in[4], (const float*)d_in[7], (const float*)d_in[10] };
    const float* Ws[3] = { (const float*)d_in[5], (const float*)d_in[8], (const float*)d_in[11] };
    const float* b[3]  = { (const float*)d_in[6], (const float*)d_in[9], (const float*)d_in[12] };

    // Workspace (~78 MB):
    //   agg   uint[NN*64]             25.6 MB
    //   xbuf0/xbuf1 ushort[(NN+1)*64] 2 x 12.8 MB (row NN = zero row)
    //   wt ushort[3][12288]
    //   esrc int[2*NN*CAP + 4]        25.6 MB fixed buckets + sentinel quad
    //                                 (UNINITIALIZED except sentinel; garbage
    //                                 masked in-register by the aggregate)
    //   cnt2 int[2NN]                 cursors -> per-(dst,rel) counts
    uint*   agg   = (uint*)d_ws;
    ushort* xbuf0 = (ushort*)(agg + (size_t)NN * 64);
    ushort* xbuf1 = xbuf0 + (size_t)(NN + 1) * DIM;
    ushort* wt    = xbuf1 + (size_t)(NN + 1) * DIM;
    int* esrc    = (int*)(wt + 3 * 12288);
    int* cnt2    = esrc + 2 * NN * CAP + 4;
    float* outF  = (float*)d_out;

    const dim3 tb(256);
    const int fgrid = G_ZC + G_CONV + 1 + 144;   // 6591
    const int tgrid = (NN + 63) / 64;            // 1563
    const int agrid = NN / 32;                   // 3125

    // 1 launch: prep (cnt2 zero, convert, zero-rows, sentinel, weights)
    front_end<<<fgrid, tb, 0, stream>>>(esrc, cnt2, feat, xbuf0, xbuf1,
                                        W[0], Ws[0], W[1], Ws[1], W[2], Ws[2], wt);
    // 1 launch: one-pass bucket CSR fill (clean L2 -> ~63us)
    fill_direct<<<FGRID, tb, 0, stream>>>(src, dst, et, cnt2, esrc);

    // Layer 0: xbuf0 -> xbuf1 = f16(relu(out0))
    rgcn_aggregate_g4<<<agrid, tb, 0, stream>>>((const uint4*)xbuf0, cnt2, esrc, (uint4*)agg);
    rgcn_transform_mfma<<<tgrid, tb, 0, stream>>>((const ushort*)agg, xbuf0, wt, b[0], nullptr, xbuf1, 0);
    // Layer 1: xbuf1 -> xbuf0
    rgcn_aggregate_g4<<<agrid, tb, 0, stream>>>((const uint4*)xbuf1, cnt2, esrc, (uint4*)agg);
    rgcn_transform_mfma<<<tgrid, tb, 0, stream>>>((const ushort*)agg, xbuf1, wt + 12288, b[1], nullptr, xbuf0, 0);
    // Layer 2: xbuf0 -> d_out (fp32, no activation)
    rgcn_aggregate_g4<<<agrid, tb, 0, stream>>>((const uint4*)xbuf0, cnt2, esrc, (uint4*)agg);
    rgcn_transform_mfma<<<tgrid, tb, 0, stream>>>((const ushort*)agg, xbuf0, wt + 2 * 12288, b[2], outF, nullptr, 1);
}